// Round 12
// baseline (154.139 us; speedup 1.0000x reference)
//
#include <hip/hip_runtime.h>
#include <hip/hip_bf16.h>

typedef unsigned short ushort_t;
typedef __attribute__((ext_vector_type(8))) short short8;
typedef __attribute__((ext_vector_type(4))) float floatx4;

#define TWO_PI 6.28318530717958647692f

__device__ __forceinline__ float bf2f(ushort_t u) {
  union { unsigned u; float f; } v; v.u = ((unsigned)u) << 16; return v.f;
}
__device__ __forceinline__ unsigned pk(float a, float b) {
  union { __hip_bfloat162 h2; unsigned u; } v;
  v.h2 = __float22bfloat162_rn(make_float2(a, b));
  return v.u;
}
__device__ __forceinline__ float ldin(const void* p, int idx, bool bf) {
  return bf ? bf2f(((const ushort_t*)p)[idx]) : ((const float*)p)[idx];
}
__device__ __forceinline__ bool detect_bf16(const void* xv) {
  const ushort_t* us = (const ushort_t*)xv;
  unsigned u = us[threadIdx.x & 63];
  int e = (u >> 7) & 0xFF;
  bool good = (e >= 110) && (e <= 133);
  unsigned long long m = __ballot(good);
  return __builtin_popcountll(m) >= 52;
}
__device__ __forceinline__ uint4 pack8f(const float* p) {
  float4 a = *(const float4*)p, b = *(const float4*)(p + 4);
  uint4 r;
  r.x = pk(a.x, a.y); r.y = pk(a.z, a.w);
  r.z = pk(b.x, b.y); r.w = pk(b.z, b.w);
  return r;
}

// async global->LDS, 16B per lane; LDS dest = wave-uniform base + lane*16
__device__ __forceinline__ void gload16(const void* g, void* l) {
  __builtin_amdgcn_global_load_lds(
      (const __attribute__((address_space(1))) unsigned*)g,
      (__attribute__((address_space(3))) unsigned*)l, 16, 0, 0);
}

// ---------------------------------------------------------------------------
// Prep (fused): blocks 0..255 = featT, blocks 256..511 = wconv (shuffle baked).
// ---------------------------------------------------------------------------
__global__ __launch_bounds__(256) void paiconv_prep(
    const void* __restrict__ xprobe, const void* __restrict__ feat,
    ushort_t* __restrict__ Ft, const void* __restrict__ W,
    ushort_t* __restrict__ Wc)
{
  const bool bfm = detect_bf16(xprobe);
  const int t = threadIdx.x;
  __shared__ ushort_t tile[64 * 72];

  if (blockIdx.x >= 256) {
    int i = ((blockIdx.x - 256) * 256 + t) << 3;
    int n = i >> 12, rem = i & 4095;
    int c = rem >> 5, j = rem & 31;
    int src = (n << 12) + (((c & 31) * 4 + (c >> 5)) << 5) + j;
    if (bfm) *(uint4*)(Wc + i) = *(const uint4*)((const ushort_t*)W + src);
    else     *(uint4*)(Wc + i) = pack8f((const float*)W + src);
    return;
  }

  const int bb = blockIdx.x >> 5;
  const int n0 = (blockIdx.x & 31) << 6;
  {
    const int c = t & 63, ng = t >> 6;
    size_t base = (((size_t)(bb * 64 + c)) << 11) + n0 + (ng << 4);
    ushort_t v[16];
    if (bfm) {
      const ushort_t* fp_ = (const ushort_t*)feat + base;
      uint4 a = *(const uint4*)fp_, b2 = *(const uint4*)(fp_ + 8);
      unsigned uu[8] = {a.x, a.y, a.z, a.w, b2.x, b2.y, b2.z, b2.w};
#pragma unroll
      for (int e = 0; e < 8; ++e) {
        v[2 * e] = (ushort_t)(uu[e] & 0xffff);
        v[2 * e + 1] = (ushort_t)(uu[e] >> 16);
      }
    } else {
      const float* fp_ = (const float*)feat + base;
#pragma unroll
      for (int k = 0; k < 16; k += 2) {
        unsigned u = pk(fp_[k], fp_[k + 1]);
        v[k] = (ushort_t)(u & 0xffff);
        v[k + 1] = (ushort_t)(u >> 16);
      }
    }
#pragma unroll
    for (int k = 0; k < 16; ++k) tile[(ng * 16 + k) * 72 + c] = v[k];
  }
  __syncthreads();
  {
    const int nn = t >> 2, qtr = t & 3;
    uint4 w0 = *(const uint4*)(tile + nn * 72 + qtr * 16);
    uint4 w1 = *(const uint4*)(tile + nn * 72 + qtr * 16 + 8);
    ushort_t* dst = Ft + (((size_t)(bb * 2048 + n0 + nn)) << 6) + (qtr << 4);
    *(uint4*)dst = w0;
    *(uint4*)(dst + 8) = w1;
  }
}

// ---------------------------------------------------------------------------
// Phase 1: 2 points/block, point-sequential sF, kern/mlpb hoisted to
// registers -> LDS 27136 B alloc -> 6 blocks/CU.  (r7-proven optimum)
// ---------------------------------------------------------------------------
#define SFPT 5184
__global__ __launch_bounds__(256) void paiconv_phase1(
    const void* __restrict__ x,       // [8,3,2048]
    const ushort_t* __restrict__ Ft,  // [16384][64] bf16
    const int*  __restrict__ nbr,     // [8,2048,32]
    const void* __restrict__ Brff,    // [7,32]
    const void* __restrict__ kern,    // [3,32]
    const void* __restrict__ mlpw,    // [64,64]
    const void* __restrict__ mlpb,    // [64]
    ushort_t*   __restrict__ Ag)      // [16384,4096] bf16
{
  const bool bfm = detect_bf16(x);
  const int t = threadIdx.x;
  const int p0 = blockIdx.x << 1;
  const int b  = p0 >> 11;
  const int w = t >> 6, lane = t & 63, lrow = lane & 15, quad = lane >> 4;

  __shared__ ushort_t sRt[64 * 72];     // 9.2 KB
  __shared__ ushort_t sF[SFPT];         // 10.4 KB (one point at a time)
  __shared__ ushort_t sP[2 * 32 * 40];  // 5.1 KB
  __shared__ float sRel[2][32][3];
  __shared__ float sDis[2][32];
  __shared__ float sRep[2][3];
  __shared__ float sBr[224];

  // gather prefetch: 16 channels (2 uint4)/thread
  const int gpt = t >> 7, gj = (t >> 2) & 31, gch = t & 3;
  const int gidx = nbr[((p0 + gpt) << 5) + gj];
  const ushort_t* gfr = Ft + (((size_t)(b * 2048 + gidx)) << 6) + (gch << 4);
  uint4 g0 = ((const uint4*)gfr)[0];
  uint4 g1 = ((const uint4*)gfr)[1];

  // per-thread constants hoisted to registers (were sKn / sMb in LDS)
  const int pj = t & 31;
  const float kn0 = ldin(kern, pj, bfm);
  const float kn1 = ldin(kern, 32 + pj, bfm);
  const float kn2 = ldin(kern, 64 + pj, bfm);
  const int mc = (w << 4) + lrow;
  const float bv = ldin(mlpb, mc, bfm);

  short8 mb0, mb1;
  if (bfm) {
    const ushort_t* mp = (const ushort_t*)mlpw + mc * 64;
    mb0 = *(const short8*)(mp + (quad << 3));
    mb1 = *(const short8*)(mp + 32 + (quad << 3));
  } else {
    const float* mp = (const float*)mlpw + mc * 64;
    uint4 u0 = pack8f(mp + (quad << 3));
    uint4 u1 = pack8f(mp + 32 + (quad << 3));
    mb0 = *(short8*)&u0;
    mb1 = *(short8*)&u1;
  }

  if (t < 224) sBr[t] = ldin(Brff, t, bfm);
  if (t < 64) {
    int pt = t >> 5, i = t & 31;
    int p = p0 + pt;
    int idx  = nbr[(p << 5) + i];
    int idx0 = nbr[(p << 5)];
    int xo = b * 6144;
    float rx = ldin(x, xo + idx0, bfm);
    float ry = ldin(x, xo + 2048 + idx0, bfm);
    float rz = ldin(x, xo + 4096 + idx0, bfm);
    float cx = ldin(x, xo + idx, bfm);
    float cy = ldin(x, xo + 2048 + idx, bfm);
    float cz = ldin(x, xo + 4096 + idx, bfm);
    float dx = cx - rx, dy = cy - ry, dz = cz - rz;
    sRel[pt][i][0] = dx; sRel[pt][i][1] = dy; sRel[pt][i][2] = dz;
    sDis[pt][i] = sqrtf(dx * dx + dy * dy + dz * dz);
    if (i == 0) { sRep[pt][0] = rx; sRep[pt][1] = ry; sRep[pt][2] = rz; }
  }
  __syncthreads();   // b1

  // ---- I1: R^T build (all 256) + perm build (t<128) ----
  {
    int jn = t >> 2, mh = (t & 3) << 3;
    int pt = jn >> 5, j = jn & 31;
    float pos[7];
    pos[0] = TWO_PI * sRep[pt][0]; pos[1] = TWO_PI * sRep[pt][1];
    pos[2] = TWO_PI * sRep[pt][2];
    pos[3] = TWO_PI * sRel[pt][j][0]; pos[4] = TWO_PI * sRel[pt][j][1];
    pos[5] = TWO_PI * sRel[pt][j][2];
    pos[6] = TWO_PI * sDis[pt][j];
    unsigned sw[4], cw[4];
#pragma unroll
    for (int mm = 0; mm < 8; mm += 2) {
      float a0 = 0.f, a1 = 0.f;
#pragma unroll
      for (int d = 0; d < 7; ++d) {
        a0 += pos[d] * sBr[d * 32 + mh + mm];
        a1 += pos[d] * sBr[d * 32 + mh + mm + 1];
      }
      sw[mm >> 1] = pk(__sinf(a0), __sinf(a1));
      cw[mm >> 1] = pk(__cosf(a0), __cosf(a1));
    }
    ushort_t* rb = sRt + jn * 72;
    *(uint4*)(rb + mh)      = make_uint4(sw[0], sw[1], sw[2], sw[3]);
    *(uint4*)(rb + 32 + mh) = make_uint4(cw[0], cw[1], cw[2], cw[3]);
  }
  if (t < 128) {
    int pt = t >> 6, h = (t >> 5) & 1;
    float col[16];
    float s1 = 0.f;
#pragma unroll
    for (int il = 0; il < 16; ++il) {
      int i = h * 16 + il;
      float v = sRel[pt][i][0] * kn0 + sRel[pt][i][1] * kn1 + sRel[pt][i][2] * kn2;
      if (i == 0 && pj == 0) v += 1.0f;
      v = fmaxf(v, 0.f);
      col[il] = v; s1 += v;
    }
    s1 += __shfl_xor(s1, 32, 64);
    float inv1 = 1.0f / (s1 + 1e-6f);
    float s2 = 0.f;
#pragma unroll
    for (int il = 0; il < 16; ++il) { float v = col[il] * inv1; v = v * v; col[il] = v; s2 += v; }
    s2 += __shfl_xor(s2, 32, 64);
    float inv2 = 1.0f / (s2 + 1e-6f);
    unsigned pw[8];
#pragma unroll
    for (int il = 0; il < 16; il += 2) {
      float v0 = col[il] * inv2;     v0 = (v0 > 0.1f) ? v0 : 0.f;
      float v1 = col[il + 1] * inv2; v1 = (v1 > 0.1f) ? v1 : 0.f;
      pw[il >> 1] = pk(v0, v1);
    }
    ushort_t* dst = sP + pt * 1280 + pj * 40 + h * 16;
    *(uint4*)dst       = make_uint4(pw[0], pw[1], pw[2], pw[3]);
    *(uint4*)(dst + 8) = make_uint4(pw[4], pw[5], pw[6], pw[7]);
  }
  __syncthreads();   // b2

  const int rbase = (64 + mc) * 40 + ((4 + w) << 3);

#pragma unroll
  for (int pt = 0; pt < 2; ++pt) {
    // ---- fill sF for point pt ----
    {
#pragma unroll
      for (int half = 0; half < 2; ++half) {
        int mt = pt * 2 + half;
        const ushort_t* rp = sRt + (mt * 16 + lrow) * 72 + (quad << 3);
        short8 a0 = *(const short8*)rp;
        short8 a1 = *(const short8*)(rp + 32);
        floatx4 acc = {0.f, 0.f, 0.f, 0.f};
        acc = __builtin_amdgcn_mfma_f32_16x16x32_bf16(a0, mb0, acc, 0, 0, 0);
        acc = __builtin_amdgcn_mfma_f32_16x16x32_bf16(a1, mb1, acc, 0, 0, 0);
        int j0 = (half << 4) + (quad << 2);
        *(uint2*)(sF + rbase + j0) =
            make_uint2(pk(acc[0] + bv, acc[1] + bv), pk(acc[2] + bv, acc[3] + bv));
      }
      if (gpt == pt) {
        ushort_t* fp_ = sF + gch * 648 + gj;
        unsigned uu[8] = {g0.x, g0.y, g0.z, g0.w, g1.x, g1.y, g1.z, g1.w};
#pragma unroll
        for (int u = 0; u < 8; ++u) {
          fp_[(2 * u) * 40]     = (ushort_t)(uu[u] & 0xffff);
          fp_[(2 * u + 1) * 40] = (ushort_t)(uu[u] >> 16);
        }
      }
    }
    __syncthreads();   // b3 / b5

    // ---- F@P via MFMA -> global A for point pt ----
    {
      const ushort_t* Pp = sP + pt * 1280;
      short8 a0 = *(const short8*)(Pp + lrow * 40 + (quad << 3));
      short8 a1 = *(const short8*)(Pp + (16 + lrow) * 40 + (quad << 3));
      size_t prow = ((size_t)(p0 + pt)) << 12;
#pragma unroll
      for (int nt = 0; nt < 2; ++nt) {
        int blk = w * 2 + nt;
        int cidx = (blk << 4) + lrow;
        short8 bfg = *(const short8*)(sF + cidx * 40 + (blk << 3) + (quad << 3));
        floatx4 z = {0.f, 0.f, 0.f, 0.f};
        floatx4 c0 = __builtin_amdgcn_mfma_f32_16x16x32_bf16(a0, bfg, z, 0, 0, 0);
        floatx4 c1 = __builtin_amdgcn_mfma_f32_16x16x32_bf16(a1, bfg, z, 0, 0, 0);
        ushort_t* ad = Ag + prow + cidx * 32 + (quad << 2);
        *(uint2*)ad        = make_uint2(pk(c0[0], c0[1]), pk(c0[2], c0[3]));
        *(uint2*)(ad + 16) = make_uint2(pk(c1[0], c1[1]), pk(c1[2], c1[3]));
      }
    }
    if (pt == 0) __syncthreads();   // b4
  }
}

// ---------------------------------------------------------------------------
// GEMM (full-K, fused epilogue): BM=64 BN=128, K=4096 in one block, grid 256,
// 512 threads, wave-tile 32x32, acc[2][2]. global_load_lds DMA staging with
// XOR chunk swizzle, now QUAD-buffered (96 KB LDS) with depth-2 prefetch and
// ONE barrier per K-tile: stage target (k+3)&3 never collides with the
// compute buffer k&3, and the slot-k barrier already orders all COMPUTE(k-1)
// reads before any wave's STAGE(k+3) issue -> trailing barrier deleted
// (64 barriers instead of 128; 1 block/CU makes each barrier pure overhead).
// MFMA order identical to r7 -> bit-identical output.
// ---------------------------------------------------------------------------
__global__ __launch_bounds__(512) void paiconv_gemm(
    const void* __restrict__ xprobe,
    const ushort_t* __restrict__ A,    // [16384][4096] bf16
    const ushort_t* __restrict__ Wc,   // [128][4096] bf16 (shuffle baked)
    const void* __restrict__ bias,     // [128]
    void* __restrict__ out)            // [8][128][2048] f32|bf16
{
  const bool bfm = detect_bf16(xprobe);
  __shared__ ushort_t lsm[4 * 64 * 64 + 4 * 128 * 64];   // 96 KB
  ushort_t* lAs = lsm;                    // 4 x 8 KB
  ushort_t* lBs = lsm + 4 * 4096;         // 4 x 16 KB
  const int m0 = blockIdx.x << 6;
  const int t = threadIdx.x;
  const int w = t >> 6, lane = t & 63;
  const int wm = w & 1, wn = w >> 1, lrow = lane & 15, quad = lane >> 4;
  const int sx = lrow & 7;                // read-side XOR

  // staging geometry: thread t covers 16B chunk (t&7) of row (t>>3);
  // LDS linear => swizzle the SOURCE chunk.
  const int srow = t >> 3, schk = t & 7;
  const int gchk = schk ^ (srow & 7);
  const ushort_t* Agp  = A  + (size_t)(m0 + srow) * 4096 + (gchk << 3);
  const ushort_t* Bgp0 = Wc + (size_t)srow * 4096        + (gchk << 3);
  const ushort_t* Bgp1 = Wc + (size_t)(64 + srow) * 4096 + (gchk << 3);
  const int wb = w << 9;                  // per-wave LDS base (512 ushorts)

  floatx4 acc[2][2];
#pragma unroll
  for (int i = 0; i < 2; ++i)
#pragma unroll
    for (int j = 0; j < 2; ++j) acc[i][j] = (floatx4){0.f, 0.f, 0.f, 0.f};

#define STAGE(buf, kbn) do { int off_ = (kbn) << 6;                          \
    gload16(Agp  + off_, lAs + (buf) * 4096 + wb);                           \
    gload16(Bgp0 + off_, lBs + (buf) * 8192 + wb);                           \
    gload16(Bgp1 + off_, lBs + (buf) * 8192 + 4096 + wb); } while (0)

#define COMPUTE(buf) do {                                                    \
    const ushort_t* la_ = lAs + (buf) * 4096;                                \
    const ushort_t* lb_ = lBs + (buf) * 8192;                                \
    _Pragma("unroll")                                                        \
    for (int kk = 0; kk < 2; ++kk) {                                         \
      int ch = ((((kk << 2) + quad) ^ sx) << 3);                             \
      short8 af0 = *(const short8*)(la_ + (((wm << 5) + lrow) << 6) + ch);   \
      short8 af1 = *(const short8*)(la_ + (((wm << 5) + 16 + lrow) << 6) + ch); \
      _Pragma("unroll")                                                      \
      for (int ni = 0; ni < 2; ++ni) {                                       \
        short8 bf = *(const short8*)(lb_ + (((wn << 5) + (ni << 4) + lrow) << 6) + ch); \
        acc[0][ni] = __builtin_amdgcn_mfma_f32_16x16x32_bf16(af0, bf, acc[0][ni], 0, 0, 0); \
        acc[1][ni] = __builtin_amdgcn_mfma_f32_16x16x32_bf16(af1, bf, acc[1][ni], 0, 0, 0); \
      } } } while (0)

#define VMW(n) asm volatile("s_waitcnt vmcnt(" #n ")" ::: "memory")
#define BAR() __builtin_amdgcn_s_barrier()
#define SB0() __builtin_amdgcn_sched_barrier(0)

  STAGE(0, 0);
  STAGE(1, 1);

  for (int g = 0; g < 15; ++g) {            // tiles 0..59 (buf = tile & 3)
    const int kb = g * 4;
    STAGE(2, kb + 2); VMW(6); BAR(); SB0(); COMPUTE(0);
    STAGE(3, kb + 3); VMW(6); BAR(); SB0(); COMPUTE(1);
    STAGE(0, kb + 4); VMW(6); BAR(); SB0(); COMPUTE(2);
    STAGE(1, kb + 5); VMW(6); BAR(); SB0(); COMPUTE(3);
  }
  // tail: tiles 60(b0) 61(b1) already staged; stage 62(b2), 63(b3)
  STAGE(2, 62); VMW(6); BAR(); SB0(); COMPUTE(0);   // tile 60
  STAGE(3, 63); VMW(6); BAR(); SB0(); COMPUTE(1);   // tile 61
  VMW(3); BAR(); SB0(); COMPUTE(2);                 // tile 62
  VMW(0); BAR(); SB0(); COMPUTE(3);                 // tile 63

#undef STAGE
#undef COMPUTE
#undef VMW
#undef BAR
#undef SB0

  // ---- epilogue: bias + transpose via LDS + direct out write ----
  __syncthreads();                          // all ds_reads done; LDS reusable
  float* buf = (float*)lsm;                 // 128*65 floats = 33280 B < 96 KB
  const int b = m0 >> 11, n0 = m0 & 2047;
#pragma unroll
  for (int mi = 0; mi < 2; ++mi)
#pragma unroll
    for (int ni = 0; ni < 2; ++ni)
#pragma unroll
      for (int r = 0; r < 4; ++r) {
        int m = (wm << 5) + (mi << 4) + (quad << 2) + r;
        int n = (wn << 5) + (ni << 4) + lrow;
        buf[n * 65 + m] = acc[mi][ni][r];
      }
  __syncthreads();
#pragma unroll
  for (int i = 0; i < 4; ++i) {
    int lin = (i << 9) + t;                 // 0..2047
    int chn = lin >> 4, nl = (lin & 15) << 2;
    float vb = ldin(bias, chn, bfm);
    float v0 = buf[chn * 65 + nl + 0] + vb, v1 = buf[chn * 65 + nl + 1] + vb;
    float v2 = buf[chn * 65 + nl + 2] + vb, v3 = buf[chn * 65 + nl + 3] + vb;
    size_t o = (size_t)b * 262144 + (size_t)chn * 2048 + n0 + nl;
    if (bfm) *(uint2*)((ushort_t*)out + o) = make_uint2(pk(v0, v1), pk(v2, v3));
    else     *(float4*)((float*)out + o)   = make_float4(v0, v1, v2, v3);
  }
}

extern "C" void kernel_launch(void* const* d_in, const int* in_sizes, int n_in,
                              void* d_out, int out_size, void* d_ws, size_t ws_size,
                              hipStream_t stream) {
  const void* x     = d_in[0];
  const void* feat  = d_in[1];
  const int*  nbr   = (const int*)d_in[2];
  const void* Brff  = d_in[3];
  const void* kern  = d_in[4];
  const void* mlpw  = d_in[5];
  const void* mlpb  = d_in[6];
  const void* convw = d_in[7];
  const void* convb = d_in[8];

  char* ws = (char*)d_ws;
  ushort_t* A   = (ushort_t*)ws;                          // 128 MiB
  ushort_t* Wcv = (ushort_t*)(ws + (size_t)134217728);    // 1 MiB
  ushort_t* Ft  = (ushort_t*)(ws + (size_t)152043520);    // 2 MiB

  paiconv_prep<<<512, 256, 0, stream>>>(x, feat, Ft, convw, Wcv);
  paiconv_phase1<<<8192, 256, 0, stream>>>(x, Ft, nbr, Brff, kern, mlpw, mlpb, A);
  paiconv_gemm<<<256, 512, 0, stream>>>(x, A, Wcv, convb, d_out);
}

// Round 13
// 148.497 us; speedup vs baseline: 1.0380x; 1.0380x over previous
//
#include <hip/hip_runtime.h>
#include <hip/hip_bf16.h>

typedef unsigned short ushort_t;
typedef __attribute__((ext_vector_type(8))) short short8;
typedef __attribute__((ext_vector_type(4))) float floatx4;

#define TWO_PI 6.28318530717958647692f

__device__ __forceinline__ float bf2f(ushort_t u) {
  union { unsigned u; float f; } v; v.u = ((unsigned)u) << 16; return v.f;
}
__device__ __forceinline__ unsigned pk(float a, float b) {
  union { __hip_bfloat162 h2; unsigned u; } v;
  v.h2 = __float22bfloat162_rn(make_float2(a, b));
  return v.u;
}
__device__ __forceinline__ float ldin(const void* p, int idx, bool bf) {
  return bf ? bf2f(((const ushort_t*)p)[idx]) : ((const float*)p)[idx];
}
__device__ __forceinline__ bool detect_bf16(const void* xv) {
  const ushort_t* us = (const ushort_t*)xv;
  unsigned u = us[threadIdx.x & 63];
  int e = (u >> 7) & 0xFF;
  bool good = (e >= 110) && (e <= 133);
  unsigned long long m = __ballot(good);
  return __builtin_popcountll(m) >= 52;
}
__device__ __forceinline__ uint4 pack8f(const float* p) {
  float4 a = *(const float4*)p, b = *(const float4*)(p + 4);
  uint4 r;
  r.x = pk(a.x, a.y); r.y = pk(a.z, a.w);
  r.z = pk(b.x, b.y); r.w = pk(b.z, b.w);
  return r;
}

// async global->LDS, 16B per lane; LDS dest = wave-uniform base + lane*16
__device__ __forceinline__ void gload16(const void* g, void* l) {
  __builtin_amdgcn_global_load_lds(
      (const __attribute__((address_space(1))) unsigned*)g,
      (__attribute__((address_space(3))) unsigned*)l, 16, 0, 0);
}

// ---------------------------------------------------------------------------
// Prep (fused): blocks 0..255 = featT, blocks 256..511 = wconv (shuffle baked).
// ---------------------------------------------------------------------------
__global__ __launch_bounds__(256) void paiconv_prep(
    const void* __restrict__ xprobe, const void* __restrict__ feat,
    ushort_t* __restrict__ Ft, const void* __restrict__ W,
    ushort_t* __restrict__ Wc)
{
  const bool bfm = detect_bf16(xprobe);
  const int t = threadIdx.x;
  __shared__ ushort_t tile[64 * 72];

  if (blockIdx.x >= 256) {
    int i = ((blockIdx.x - 256) * 256 + t) << 3;
    int n = i >> 12, rem = i & 4095;
    int c = rem >> 5, j = rem & 31;
    int src = (n << 12) + (((c & 31) * 4 + (c >> 5)) << 5) + j;
    if (bfm) *(uint4*)(Wc + i) = *(const uint4*)((const ushort_t*)W + src);
    else     *(uint4*)(Wc + i) = pack8f((const float*)W + src);
    return;
  }

  const int bb = blockIdx.x >> 5;
  const int n0 = (blockIdx.x & 31) << 6;
  {
    const int c = t & 63, ng = t >> 6;
    size_t base = (((size_t)(bb * 64 + c)) << 11) + n0 + (ng << 4);
    ushort_t v[16];
    if (bfm) {
      const ushort_t* fp_ = (const ushort_t*)feat + base;
      uint4 a = *(const uint4*)fp_, b2 = *(const uint4*)(fp_ + 8);
      unsigned uu[8] = {a.x, a.y, a.z, a.w, b2.x, b2.y, b2.z, b2.w};
#pragma unroll
      for (int e = 0; e < 8; ++e) {
        v[2 * e] = (ushort_t)(uu[e] & 0xffff);
        v[2 * e + 1] = (ushort_t)(uu[e] >> 16);
      }
    } else {
      const float* fp_ = (const float*)feat + base;
#pragma unroll
      for (int k = 0; k < 16; k += 2) {
        unsigned u = pk(fp_[k], fp_[k + 1]);
        v[k] = (ushort_t)(u & 0xffff);
        v[k + 1] = (ushort_t)(u >> 16);
      }
    }
#pragma unroll
    for (int k = 0; k < 16; ++k) tile[(ng * 16 + k) * 72 + c] = v[k];
  }
  __syncthreads();
  {
    const int nn = t >> 2, qtr = t & 3;
    uint4 w0 = *(const uint4*)(tile + nn * 72 + qtr * 16);
    uint4 w1 = *(const uint4*)(tile + nn * 72 + qtr * 16 + 8);
    ushort_t* dst = Ft + (((size_t)(bb * 2048 + n0 + nn)) << 6) + (qtr << 4);
    *(uint4*)dst = w0;
    *(uint4*)(dst + 8) = w1;
  }
}

// ---------------------------------------------------------------------------
// Phase 1: 2 points/block, point-sequential sF, kern/mlpb hoisted to
// registers -> LDS 27136 B alloc -> 6 blocks/CU.  (session-proven optimum;
// scatter re-layout, 4-pt scaling both regressed — bank-tuned local optimum)
// ---------------------------------------------------------------------------
#define SFPT 5184
__global__ __launch_bounds__(256) void paiconv_phase1(
    const void* __restrict__ x,       // [8,3,2048]
    const ushort_t* __restrict__ Ft,  // [16384][64] bf16
    const int*  __restrict__ nbr,     // [8,2048,32]
    const void* __restrict__ Brff,    // [7,32]
    const void* __restrict__ kern,    // [3,32]
    const void* __restrict__ mlpw,    // [64,64]
    const void* __restrict__ mlpb,    // [64]
    ushort_t*   __restrict__ Ag)      // [16384,4096] bf16
{
  const bool bfm = detect_bf16(x);
  const int t = threadIdx.x;
  const int p0 = blockIdx.x << 1;
  const int b  = p0 >> 11;
  const int w = t >> 6, lane = t & 63, lrow = lane & 15, quad = lane >> 4;

  __shared__ ushort_t sRt[64 * 72];     // 9.2 KB
  __shared__ ushort_t sF[SFPT];         // 10.4 KB (one point at a time)
  __shared__ ushort_t sP[2 * 32 * 40];  // 5.1 KB
  __shared__ float sRel[2][32][3];
  __shared__ float sDis[2][32];
  __shared__ float sRep[2][3];
  __shared__ float sBr[224];

  // gather prefetch: 16 channels (2 uint4)/thread
  const int gpt = t >> 7, gj = (t >> 2) & 31, gch = t & 3;
  const int gidx = nbr[((p0 + gpt) << 5) + gj];
  const ushort_t* gfr = Ft + (((size_t)(b * 2048 + gidx)) << 6) + (gch << 4);
  uint4 g0 = ((const uint4*)gfr)[0];
  uint4 g1 = ((const uint4*)gfr)[1];

  // per-thread constants hoisted to registers (were sKn / sMb in LDS)
  const int pj = t & 31;
  const float kn0 = ldin(kern, pj, bfm);
  const float kn1 = ldin(kern, 32 + pj, bfm);
  const float kn2 = ldin(kern, 64 + pj, bfm);
  const int mc = (w << 4) + lrow;
  const float bv = ldin(mlpb, mc, bfm);

  short8 mb0, mb1;
  if (bfm) {
    const ushort_t* mp = (const ushort_t*)mlpw + mc * 64;
    mb0 = *(const short8*)(mp + (quad << 3));
    mb1 = *(const short8*)(mp + 32 + (quad << 3));
  } else {
    const float* mp = (const float*)mlpw + mc * 64;
    uint4 u0 = pack8f(mp + (quad << 3));
    uint4 u1 = pack8f(mp + 32 + (quad << 3));
    mb0 = *(short8*)&u0;
    mb1 = *(short8*)&u1;
  }

  if (t < 224) sBr[t] = ldin(Brff, t, bfm);
  if (t < 64) {
    int pt = t >> 5, i = t & 31;
    int p = p0 + pt;
    int idx  = nbr[(p << 5) + i];
    int idx0 = nbr[(p << 5)];
    int xo = b * 6144;
    float rx = ldin(x, xo + idx0, bfm);
    float ry = ldin(x, xo + 2048 + idx0, bfm);
    float rz = ldin(x, xo + 4096 + idx0, bfm);
    float cx = ldin(x, xo + idx, bfm);
    float cy = ldin(x, xo + 2048 + idx, bfm);
    float cz = ldin(x, xo + 4096 + idx, bfm);
    float dx = cx - rx, dy = cy - ry, dz = cz - rz;
    sRel[pt][i][0] = dx; sRel[pt][i][1] = dy; sRel[pt][i][2] = dz;
    sDis[pt][i] = sqrtf(dx * dx + dy * dy + dz * dz);
    if (i == 0) { sRep[pt][0] = rx; sRep[pt][1] = ry; sRep[pt][2] = rz; }
  }
  __syncthreads();   // b1

  // ---- I1: R^T build (all 256) + perm build (t<128) ----
  {
    int jn = t >> 2, mh = (t & 3) << 3;
    int pt = jn >> 5, j = jn & 31;
    float pos[7];
    pos[0] = TWO_PI * sRep[pt][0]; pos[1] = TWO_PI * sRep[pt][1];
    pos[2] = TWO_PI * sRep[pt][2];
    pos[3] = TWO_PI * sRel[pt][j][0]; pos[4] = TWO_PI * sRel[pt][j][1];
    pos[5] = TWO_PI * sRel[pt][j][2];
    pos[6] = TWO_PI * sDis[pt][j];
    unsigned sw[4], cw[4];
#pragma unroll
    for (int mm = 0; mm < 8; mm += 2) {
      float a0 = 0.f, a1 = 0.f;
#pragma unroll
      for (int d = 0; d < 7; ++d) {
        a0 += pos[d] * sBr[d * 32 + mh + mm];
        a1 += pos[d] * sBr[d * 32 + mh + mm + 1];
      }
      sw[mm >> 1] = pk(__sinf(a0), __sinf(a1));
      cw[mm >> 1] = pk(__cosf(a0), __cosf(a1));
    }
    ushort_t* rb = sRt + jn * 72;
    *(uint4*)(rb + mh)      = make_uint4(sw[0], sw[1], sw[2], sw[3]);
    *(uint4*)(rb + 32 + mh) = make_uint4(cw[0], cw[1], cw[2], cw[3]);
  }
  if (t < 128) {
    int pt = t >> 6, h = (t >> 5) & 1;
    float col[16];
    float s1 = 0.f;
#pragma unroll
    for (int il = 0; il < 16; ++il) {
      int i = h * 16 + il;
      float v = sRel[pt][i][0] * kn0 + sRel[pt][i][1] * kn1 + sRel[pt][i][2] * kn2;
      if (i == 0 && pj == 0) v += 1.0f;
      v = fmaxf(v, 0.f);
      col[il] = v; s1 += v;
    }
    s1 += __shfl_xor(s1, 32, 64);
    float inv1 = 1.0f / (s1 + 1e-6f);
    float s2 = 0.f;
#pragma unroll
    for (int il = 0; il < 16; ++il) { float v = col[il] * inv1; v = v * v; col[il] = v; s2 += v; }
    s2 += __shfl_xor(s2, 32, 64);
    float inv2 = 1.0f / (s2 + 1e-6f);
    unsigned pw[8];
#pragma unroll
    for (int il = 0; il < 16; il += 2) {
      float v0 = col[il] * inv2;     v0 = (v0 > 0.1f) ? v0 : 0.f;
      float v1 = col[il + 1] * inv2; v1 = (v1 > 0.1f) ? v1 : 0.f;
      pw[il >> 1] = pk(v0, v1);
    }
    ushort_t* dst = sP + pt * 1280 + pj * 40 + h * 16;
    *(uint4*)dst       = make_uint4(pw[0], pw[1], pw[2], pw[3]);
    *(uint4*)(dst + 8) = make_uint4(pw[4], pw[5], pw[6], pw[7]);
  }
  __syncthreads();   // b2

  const int rbase = (64 + mc) * 40 + ((4 + w) << 3);

#pragma unroll
  for (int pt = 0; pt < 2; ++pt) {
    // ---- fill sF for point pt ----
    {
#pragma unroll
      for (int half = 0; half < 2; ++half) {
        int mt = pt * 2 + half;
        const ushort_t* rp = sRt + (mt * 16 + lrow) * 72 + (quad << 3);
        short8 a0 = *(const short8*)rp;
        short8 a1 = *(const short8*)(rp + 32);
        floatx4 acc = {0.f, 0.f, 0.f, 0.f};
        acc = __builtin_amdgcn_mfma_f32_16x16x32_bf16(a0, mb0, acc, 0, 0, 0);
        acc = __builtin_amdgcn_mfma_f32_16x16x32_bf16(a1, mb1, acc, 0, 0, 0);
        int j0 = (half << 4) + (quad << 2);
        *(uint2*)(sF + rbase + j0) =
            make_uint2(pk(acc[0] + bv, acc[1] + bv), pk(acc[2] + bv, acc[3] + bv));
      }
      if (gpt == pt) {
        ushort_t* fp_ = sF + gch * 648 + gj;
        unsigned uu[8] = {g0.x, g0.y, g0.z, g0.w, g1.x, g1.y, g1.z, g1.w};
#pragma unroll
        for (int u = 0; u < 8; ++u) {
          fp_[(2 * u) * 40]     = (ushort_t)(uu[u] & 0xffff);
          fp_[(2 * u + 1) * 40] = (ushort_t)(uu[u] >> 16);
        }
      }
    }
    __syncthreads();   // b3 / b5

    // ---- F@P via MFMA -> global A for point pt ----
    {
      const ushort_t* Pp = sP + pt * 1280;
      short8 a0 = *(const short8*)(Pp + lrow * 40 + (quad << 3));
      short8 a1 = *(const short8*)(Pp + (16 + lrow) * 40 + (quad << 3));
      size_t prow = ((size_t)(p0 + pt)) << 12;
#pragma unroll
      for (int nt = 0; nt < 2; ++nt) {
        int blk = w * 2 + nt;
        int cidx = (blk << 4) + lrow;
        short8 bfg = *(const short8*)(sF + cidx * 40 + (blk << 3) + (quad << 3));
        floatx4 z = {0.f, 0.f, 0.f, 0.f};
        floatx4 c0 = __builtin_amdgcn_mfma_f32_16x16x32_bf16(a0, bfg, z, 0, 0, 0);
        floatx4 c1 = __builtin_amdgcn_mfma_f32_16x16x32_bf16(a1, bfg, z, 0, 0, 0);
        ushort_t* ad = Ag + prow + cidx * 32 + (quad << 2);
        *(uint2*)ad        = make_uint2(pk(c0[0], c0[1]), pk(c0[2], c0[3]));
        *(uint2*)(ad + 16) = make_uint2(pk(c1[0], c1[1]), pk(c1[2], c1[3]));
      }
    }
    if (pt == 0) __syncthreads();   // b4
  }
}

// ---------------------------------------------------------------------------
// GEMM (full-K, fused epilogue): BM=64 BN=128, K=4096 in one block, grid 256,
// 512 threads, wave-tile 32x32, acc[2][2]. global_load_lds DMA staging with
// XOR chunk swizzle, triple-buffer depth-2 counted vmcnt(6). Single f32
// accumulation; epilogue: bias + LDS transpose + direct out write.
// (session optimum: 149.8 us total; BM=32, split-K, 2-blk/CU, quad-buffer
// single-barrier variants all measured neutral or worse.)
// ---------------------------------------------------------------------------
__global__ __launch_bounds__(512) void paiconv_gemm(
    const void* __restrict__ xprobe,
    const ushort_t* __restrict__ A,    // [16384][4096] bf16
    const ushort_t* __restrict__ Wc,   // [128][4096] bf16 (shuffle baked)
    const void* __restrict__ bias,     // [128]
    void* __restrict__ out)            // [8][128][2048] f32|bf16
{
  const bool bfm = detect_bf16(xprobe);
  __shared__ ushort_t lsm[3 * 64 * 64 + 3 * 128 * 64];   // 72 KB
  ushort_t* lAs = lsm;                    // 3 x 8 KB
  ushort_t* lBs = lsm + 3 * 4096;         // 3 x 16 KB
  const int m0 = blockIdx.x << 6;
  const int t = threadIdx.x;
  const int w = t >> 6, lane = t & 63;
  const int wm = w & 1, wn = w >> 1, lrow = lane & 15, quad = lane >> 4;
  const int sx = lrow & 7;                // read-side XOR

  // staging geometry: thread t covers 16B chunk (t&7) of row (t>>3);
  // LDS linear => swizzle the SOURCE chunk.
  const int srow = t >> 3, schk = t & 7;
  const int gchk = schk ^ (srow & 7);
  const ushort_t* Agp  = A  + (size_t)(m0 + srow) * 4096 + (gchk << 3);
  const ushort_t* Bgp0 = Wc + (size_t)srow * 4096        + (gchk << 3);
  const ushort_t* Bgp1 = Wc + (size_t)(64 + srow) * 4096 + (gchk << 3);
  const int wb = w << 9;                  // per-wave LDS base (512 ushorts)

  floatx4 acc[2][2];
#pragma unroll
  for (int i = 0; i < 2; ++i)
#pragma unroll
    for (int j = 0; j < 2; ++j) acc[i][j] = (floatx4){0.f, 0.f, 0.f, 0.f};

#define STAGE(buf, kbn) do { int off_ = (kbn) << 6;                          \
    gload16(Agp  + off_, lAs + (buf) * 4096 + wb);                           \
    gload16(Bgp0 + off_, lBs + (buf) * 8192 + wb);                           \
    gload16(Bgp1 + off_, lBs + (buf) * 8192 + 4096 + wb); } while (0)

#define COMPUTE(buf) do {                                                    \
    const ushort_t* la_ = lAs + (buf) * 4096;                                \
    const ushort_t* lb_ = lBs + (buf) * 8192;                                \
    _Pragma("unroll")                                                        \
    for (int kk = 0; kk < 2; ++kk) {                                         \
      int ch = ((((kk << 2) + quad) ^ sx) << 3);                             \
      short8 af0 = *(const short8*)(la_ + (((wm << 5) + lrow) << 6) + ch);   \
      short8 af1 = *(const short8*)(la_ + (((wm << 5) + 16 + lrow) << 6) + ch); \
      _Pragma("unroll")                                                      \
      for (int ni = 0; ni < 2; ++ni) {                                       \
        short8 bf = *(const short8*)(lb_ + (((wn << 5) + (ni << 4) + lrow) << 6) + ch); \
        acc[0][ni] = __builtin_amdgcn_mfma_f32_16x16x32_bf16(af0, bf, acc[0][ni], 0, 0, 0); \
        acc[1][ni] = __builtin_amdgcn_mfma_f32_16x16x32_bf16(af1, bf, acc[1][ni], 0, 0, 0); \
      } } } while (0)

#define VMW(n) asm volatile("s_waitcnt vmcnt(" #n ")" ::: "memory")
#define BAR() __builtin_amdgcn_s_barrier()
#define SB0() __builtin_amdgcn_sched_barrier(0)

  STAGE(0, 0);
  STAGE(1, 1);

  for (int g = 0; g < 20; ++g) {            // tiles 0..59
    const int kb = g * 3;
    STAGE(2, kb + 2); VMW(6); BAR(); SB0(); COMPUTE(0); BAR();
    STAGE(0, kb + 3); VMW(6); BAR(); SB0(); COMPUTE(1); BAR();
    STAGE(1, kb + 4); VMW(6); BAR(); SB0(); COMPUTE(2); BAR();
  }
  // tail: tiles 60(b0) 61(b1) already staged; stage 62(b2), 63(b0)
  STAGE(2, 62); VMW(6); BAR(); SB0(); COMPUTE(0); BAR();
  STAGE(0, 63); VMW(6); BAR(); SB0(); COMPUTE(1); BAR();
  VMW(3); BAR(); SB0(); COMPUTE(2);
  VMW(0); BAR(); SB0(); COMPUTE(0);

#undef STAGE
#undef COMPUTE
#undef VMW
#undef BAR
#undef SB0

  // ---- epilogue: bias + transpose via LDS + direct out write ----
  __syncthreads();                          // all ds_reads done; LDS reusable
  float* buf = (float*)lsm;                 // 128*65 floats = 33280 B < 72 KB
  const int b = m0 >> 11, n0 = m0 & 2047;
#pragma unroll
  for (int mi = 0; mi < 2; ++mi)
#pragma unroll
    for (int ni = 0; ni < 2; ++ni)
#pragma unroll
      for (int r = 0; r < 4; ++r) {
        int m = (wm << 5) + (mi << 4) + (quad << 2) + r;
        int n = (wn << 5) + (ni << 4) + lrow;
        buf[n * 65 + m] = acc[mi][ni][r];
      }
  __syncthreads();
#pragma unroll
  for (int i = 0; i < 4; ++i) {
    int lin = (i << 9) + t;                 // 0..2047
    int chn = lin >> 4, nl = (lin & 15) << 2;
    float vb = ldin(bias, chn, bfm);
    float v0 = buf[chn * 65 + nl + 0] + vb, v1 = buf[chn * 65 + nl + 1] + vb;
    float v2 = buf[chn * 65 + nl + 2] + vb, v3 = buf[chn * 65 + nl + 3] + vb;
    size_t o = (size_t)b * 262144 + (size_t)chn * 2048 + n0 + nl;
    if (bfm) *(uint2*)((ushort_t*)out + o) = make_uint2(pk(v0, v1), pk(v2, v3));
    else     *(float4*)((float*)out + o)   = make_float4(v0, v1, v2, v3);
  }
}

extern "C" void kernel_launch(void* const* d_in, const int* in_sizes, int n_in,
                              void* d_out, int out_size, void* d_ws, size_t ws_size,
                              hipStream_t stream) {
  const void* x     = d_in[0];
  const void* feat  = d_in[1];
  const int*  nbr   = (const int*)d_in[2];
  const void* Brff  = d_in[3];
  const void* kern  = d_in[4];
  const void* mlpw  = d_in[5];
  const void* mlpb  = d_in[6];
  const void* convw = d_in[7];
  const void* convb = d_in[8];

  char* ws = (char*)d_ws;
  ushort_t* A   = (ushort_t*)ws;                          // 128 MiB
  ushort_t* Wcv = (ushort_t*)(ws + (size_t)134217728);    // 1 MiB
  ushort_t* Ft  = (ushort_t*)(ws + (size_t)152043520);    // 2 MiB

  paiconv_prep<<<512, 256, 0, stream>>>(x, feat, Ft, convw, Wcv);
  paiconv_phase1<<<8192, 256, 0, stream>>>(x, Ft, nbr, Brff, kern, mlpw, mlpb, A);
  paiconv_gemm<<<256, 512, 0, stream>>>(x, A, Wcv, convb, d_out);
}